// Round 1
// baseline (411.173 us; speedup 1.0000x reference)
//
#include <hip/hip_runtime.h>
#include <hip/hip_bf16.h>

#define N_ROWS 131072
#define DIM 256
#define K_CODES 1024
#define BLK_ROWS 128        // 4 waves x 32 rows
#define NCHUNK 32           // 32 codes per chunk
#define FRAG_SH 512         // shorts per fragment (64 lanes x 8 bf16)
#define CHUNK_SH (32 * FRAG_SH)   // 32 frags/chunk: [0..16)=GEMM1 A, [16..32)=GEMM2 B

typedef __attribute__((ext_vector_type(8))) short bf16x8;
typedef __attribute__((ext_vector_type(16))) float f32x16;

__device__ __forceinline__ short f2bf(float x) {
    unsigned u = __float_as_uint(x);
    u += 0x7fff + ((u >> 16) & 1);   // RNE
    return (short)(u >> 16);
}

typedef const __attribute__((address_space(1))) unsigned int* gas1_t;
typedef __attribute__((address_space(3))) unsigned int* las3_t;
__device__ __forceinline__ void gload16(const short* g, short* l) {
    // per-lane global addr (contiguous 16B/lane); wave-uniform LDS base + lane*16
    __builtin_amdgcn_global_load_lds((gas1_t)(const void*)g, (las3_t)(void*)l, 16, 0, 0);
}

// ---------------- prep: codebook -> fragment-order bf16 (one block per 32-code chunk)
__global__ void prep_kernel(const float* __restrict__ cb,
                            short* __restrict__ bg) {
    __shared__ __align__(16) float tile[32 * 264];   // [code][d] fp32, stride 264
    __shared__ float en2s[32];
    const int tid = threadIdx.x;
    const int w = tid >> 6, l = tid & 63, hf = l >> 5, c31 = l & 31;
    const int ch = blockIdx.x, cb0 = ch * 32;

#pragma unroll
    for (int it = 0; it < 8; ++it) {
        int idx = it * 256 + tid;          // float4 index
        int r = idx >> 6, c = (idx & 63) * 4;
        *(float4*)&tile[r * 264 + c] = *(const float4*)&cb[(size_t)(cb0 + r) * DIM + c];
    }
    __syncthreads();

    {   // en2[c] = exp(-||e_c||^2), 8 threads per code
        int c = tid >> 3, part = tid & 7;
        float s = 0.f;
#pragma unroll
        for (int j = 0; j < 32; ++j) {
            float v = tile[c * 264 + part * 32 + j];
            s += v * v;
        }
        s += __shfl_xor(s, 1, 64);
        s += __shfl_xor(s, 2, 64);
        s += __shfl_xor(s, 4, 64);
        if (part == 0) en2s[c] = __expf(-s);
    }
    __syncthreads();

    // GEMM1 A-frags (f = t = 0..15): lane holds E[cb0 + c31][t*16 + hf*8 + j]
#pragma unroll
    for (int i = 0; i < 4; ++i) {
        int f = i * 4 + w;
        const float* src = &tile[c31 * 264 + f * 16 + hf * 8];
        float4 v0 = *(const float4*)src;
        float4 v1 = *(const float4*)(src + 4);
        bf16x8 v;
        v[0] = f2bf(v0.x); v[1] = f2bf(v0.y); v[2] = f2bf(v0.z); v[3] = f2bf(v0.w);
        v[4] = f2bf(v1.x); v[5] = f2bf(v1.y); v[6] = f2bf(v1.z); v[7] = f2bf(v1.w);
        *(bf16x8*)&bg[ch * CHUNK_SH + f * FRAG_SH + l * 8] = v;
    }
    // GEMM2 B-frags (f = 16 + n2*2 + t2), en2-folded, kappa code order:
    // slot (hf, j) holds code (t2*2 + (j>>2))*8 + 4*hf + (j&3), matching P's A-register order
#pragma unroll
    for (int i = 0; i < 4; ++i) {
        int g = i * 4 + w;
        int n2 = g >> 1, t2 = g & 1;
        int d = n2 * 32 + c31;
        bf16x8 v;
#pragma unroll
        for (int j = 0; j < 8; ++j) {
            int c2 = (t2 * 2 + (j >> 2)) * 8 + 4 * hf + (j & 3);
            v[j] = f2bf(tile[c2 * 264 + d] * en2s[c2]);
        }
        *(bf16x8*)&bg[ch * CHUNK_SH + (16 + g) * FRAG_SH + l * 8] = v;
    }
}

// ---------------- main fused kernel ----------------
__global__ __launch_bounds__(256, 2)
void svq_kernel(const float* __restrict__ z,
                const short* __restrict__ bg,
                float* __restrict__ out,
                float* __restrict__ loss) {
    __shared__ __align__(16) short lds_b[2 * CHUNK_SH];  // 2 x 32 KB double buffer

    const int tid = threadIdx.x;
    const int w = tid >> 6, l = tid & 63, hf = l >> 5, c31 = l & 31;
    const int rowbase = blockIdx.x * BLK_ROWS + w * 32;

    // z fragments: lane holds z[rowbase + c31][t*16 + hf*8 + j].
    // Same register layout serves as MFMA B-operand (B[k=d][n=row]) for GEMM1.
    bf16x8 za[16];
    float sz2 = 0.f;   // exact fp32 sum of z^2 over this lane's 128 elements
    {
        const float* zr = z + (size_t)(rowbase + c31) * DIM + hf * 8;
#pragma unroll
        for (int t = 0; t < 16; ++t) {
            float4 v0 = *(const float4*)(zr + t * 16);
            float4 v1 = *(const float4*)(zr + t * 16 + 4);
            sz2 += v0.x*v0.x + v0.y*v0.y + v0.z*v0.z + v0.w*v0.w
                 + v1.x*v1.x + v1.y*v1.y + v1.z*v1.z + v1.w*v1.w;
            bf16x8 a;
            a[0] = f2bf(v0.x); a[1] = f2bf(v0.y); a[2] = f2bf(v0.z); a[3] = f2bf(v0.w);
            a[4] = f2bf(v1.x); a[5] = f2bf(v1.y); a[6] = f2bf(v1.z); a[7] = f2bf(v1.w);
            za[t] = a;
        }
    }

    f32x16 o[8];
#pragma unroll
    for (int i = 0; i < 8; ++i)
        o[i] = (f32x16){0.f,0.f,0.f,0.f,0.f,0.f,0.f,0.f,0.f,0.f,0.f,0.f,0.f,0.f,0.f,0.f};
    float rs0 = 0.f, rs1 = 0.f;   // sum of p over this lane's codes (two partials)
    float q0 = 0.f,  q1 = 0.f;    // sum of p*s -> z_soft . z (two partials)

    // prologue: stage chunk 0 into buffer 0
    {
        const short* sg = bg + l * 8;
#pragma unroll
        for (int i = 0; i < 8; ++i) {
            int f = i * 4 + w;
            gload16(sg + f * FRAG_SH, &lds_b[f * FRAG_SH]);
        }
    }

    for (int ch = 0; ch < NCHUNK; ++ch) {
        // drains chunk-ch staging (which had all of compute(ch-1) to overlap)
        // and makes buffer (ch+1)&1 safe to overwrite
        __syncthreads();
        if (ch + 1 < NCHUNK) {
            const short* sg = bg + (ch + 1) * CHUNK_SH + l * 8;
            short* lbase = &lds_b[((ch + 1) & 1) * CHUNK_SH];
#pragma unroll
            for (int i = 0; i < 8; ++i) {
                int f = i * 4 + w;
                gload16(sg + f * FRAG_SH, lbase + f * FRAG_SH);
            }
        }

        const short* lb = &lds_b[(ch & 1) * CHUNK_SH + l * 8];

        // GEMM1 (transposed): S^T[32 codes x 32 rows] = E . Z^T
        f32x16 s = (f32x16){0.f,0.f,0.f,0.f,0.f,0.f,0.f,0.f,0.f,0.f,0.f,0.f,0.f,0.f,0.f,0.f};
        __builtin_amdgcn_s_setprio(1);
#pragma unroll
        for (int t = 0; t < 16; ++t) {
            bf16x8 a = *(const bf16x8*)(lb + t * FRAG_SH);
            s = __builtin_amdgcn_mfma_f32_32x32x16_bf16(a, za[t], s, 0, 0, 0);
        }
        __builtin_amdgcn_s_setprio(0);

        // softmax numerators (en2 folded into GEMM2 B; ~1e-4-rel effect, below threshold)
        bf16x8 a20, a21;
#pragma unroll
        for (int reg = 0; reg < 16; ++reg) {
            float sv = s[reg];
            float p = exp2f(sv * 2.8853900818f);   // exp(2 z.e)
            if (reg & 1) { rs1 += p; q1 += p * sv; }
            else         { rs0 += p; q0 += p * sv; }
            if (reg < 8) a20[reg] = f2bf(p); else a21[reg - 8] = f2bf(p);
        }

        // GEMM2: o[32 rows x 256 d] += P . E'  (B-frags prebuilt in kappa order)
        __builtin_amdgcn_s_setprio(1);
#pragma unroll
        for (int n2 = 0; n2 < 8; ++n2) {
            bf16x8 b0 = *(const bf16x8*)(lb + (16 + n2 * 2) * FRAG_SH);
            o[n2] = __builtin_amdgcn_mfma_f32_32x32x16_bf16(a20, b0, o[n2], 0, 0, 0);
            bf16x8 b1 = *(const bf16x8*)(lb + (16 + n2 * 2 + 1) * FRAG_SH);
            o[n2] = __builtin_amdgcn_mfma_f32_32x32x16_bf16(a21, b1, o[n2], 0, 0, 0);
        }
        __builtin_amdgcn_s_setprio(0);
    }

    // combine the two half-dim/half-code lanes of each row
    float rs = rs0 + rs1, q = q0 + q1;
    float rs_t = rs + __shfl_xor(rs, 32, 64);
    float q_t  = q  + __shfl_xor(q, 32, 64);
    float inv  = 1.f / rs_t;

    // epilogue: normalize, store, accumulate loss terms.
    // Loop order = row-major per lane: each lane writes its row's 8 x 128B blocks
    // back-to-back so every HBM line is fully dirtied before eviction
    // (n2-outer order produced 2.15x WRITE_SIZE amplification).
    float zs2 = 0.f;
    const size_t ob = (size_t)rowbase * DIM;
#pragma unroll
    for (int reg = 0; reg < 16; ++reg) {
        int r = (reg & 3) + 8 * (reg >> 2) + 4 * hf;
        float iv = __shfl(inv, r, 64);
        float* orow = out + ob + (size_t)r * DIM + c31;
#pragma unroll
        for (int n2 = 0; n2 < 8; ++n2) {
            float v = o[n2][reg] * iv;
            orow[(size_t)n2 * 32] = v;
            zs2 += v * v;
        }
    }

    // loss = mean(z^2) - 2*mean(zs.z) + mean(zs^2); zs.z per row = q_t * inv
    float lacc = sz2 + zs2;
    if (hf == 0) lacc -= 2.f * q_t * inv;
#pragma unroll
    for (int off = 32; off > 0; off >>= 1) lacc += __shfl_xor(lacc, off, 64);
    if (l == 0) atomicAdd(loss, lacc * (1.f / ((float)N_ROWS * (float)DIM)));
}

extern "C" void kernel_launch(void* const* d_in, const int* in_sizes, int n_in,
                              void* d_out, int out_size, void* d_ws, size_t ws_size,
                              hipStream_t stream) {
    const float* z = (const float*)d_in[0];
    const float* cb = (const float*)d_in[1];
    float* out = (float*)d_out;

    short* bg = (short*)d_ws;    // 32 chunks * 16384 shorts = 1 MB

    float* loss = out + (size_t)N_ROWS * DIM;
    hipMemsetAsync((void*)loss, 0, sizeof(float), stream);

    prep_kernel<<<dim3(NCHUNK), dim3(256), 0, stream>>>(cb, bg);
    svq_kernel<<<dim3(N_ROWS / BLK_ROWS), dim3(256), 0, stream>>>(
        z, bg, out, loss);
}

// Round 2
// 389.095 us; speedup vs baseline: 1.0567x; 1.0567x over previous
//
#include <hip/hip_runtime.h>
#include <hip/hip_bf16.h>

#define N_ROWS 131072
#define DIM 256
#define K_CODES 1024
#define BLK_ROWS 128        // 4 waves x 32 rows
#define NCHUNK 32           // 32 codes per chunk
#define FRAG_SH 512         // shorts per fragment (64 lanes x 8 bf16)
#define CHUNK_SH (32 * FRAG_SH)   // 32 frags/chunk: [0..16)=GEMM1 A, [16..32)=GEMM2 B

typedef __attribute__((ext_vector_type(8))) short bf16x8;
typedef __attribute__((ext_vector_type(16))) float f32x16;

__device__ __forceinline__ short f2bf(float x) {
    unsigned u = __float_as_uint(x);
    u += 0x7fff + ((u >> 16) & 1);   // RNE
    return (short)(u >> 16);
}

typedef const __attribute__((address_space(1))) unsigned int* gas1_t;
typedef __attribute__((address_space(3))) unsigned int* las3_t;
__device__ __forceinline__ void gload16(const short* g, short* l) {
    // per-lane global addr (contiguous 16B/lane); wave-uniform LDS base + lane*16
    __builtin_amdgcn_global_load_lds((gas1_t)(const void*)g, (las3_t)(void*)l, 16, 0, 0);
}

// ---------------- prep: codebook -> fragment-order bf16 (one block per 32-code chunk)
__global__ void prep_kernel(const float* __restrict__ cb,
                            short* __restrict__ bg) {
    __shared__ __align__(16) float tile[32 * 264];   // [code][d] fp32, stride 264
    __shared__ float en2s[32];
    const int tid = threadIdx.x;
    const int w = tid >> 6, l = tid & 63, hf = l >> 5, c31 = l & 31;
    const int ch = blockIdx.x, cb0 = ch * 32;

#pragma unroll
    for (int it = 0; it < 8; ++it) {
        int idx = it * 256 + tid;          // float4 index
        int r = idx >> 6, c = (idx & 63) * 4;
        *(float4*)&tile[r * 264 + c] = *(const float4*)&cb[(size_t)(cb0 + r) * DIM + c];
    }
    __syncthreads();

    {   // en2[c] = exp(-||e_c||^2), 8 threads per code
        int c = tid >> 3, part = tid & 7;
        float s = 0.f;
#pragma unroll
        for (int j = 0; j < 32; ++j) {
            float v = tile[c * 264 + part * 32 + j];
            s += v * v;
        }
        s += __shfl_xor(s, 1, 64);
        s += __shfl_xor(s, 2, 64);
        s += __shfl_xor(s, 4, 64);
        if (part == 0) en2s[c] = __expf(-s);
    }
    __syncthreads();

    // GEMM1 A-frags (f = t = 0..15): lane holds E[cb0 + c31][t*16 + hf*8 + j]
#pragma unroll
    for (int i = 0; i < 4; ++i) {
        int f = i * 4 + w;
        const float* src = &tile[c31 * 264 + f * 16 + hf * 8];
        float4 v0 = *(const float4*)src;
        float4 v1 = *(const float4*)(src + 4);
        bf16x8 v;
        v[0] = f2bf(v0.x); v[1] = f2bf(v0.y); v[2] = f2bf(v0.z); v[3] = f2bf(v0.w);
        v[4] = f2bf(v1.x); v[5] = f2bf(v1.y); v[6] = f2bf(v1.z); v[7] = f2bf(v1.w);
        *(bf16x8*)&bg[ch * CHUNK_SH + f * FRAG_SH + l * 8] = v;
    }
    // GEMM2 B-frags (f = 16 + n2*2 + t2), en2-folded, kappa code order:
    // slot (hf, j) holds code (t2*2 + (j>>2))*8 + 4*hf + (j&3), matching P's A-register order
#pragma unroll
    for (int i = 0; i < 4; ++i) {
        int g = i * 4 + w;
        int n2 = g >> 1, t2 = g & 1;
        int d = n2 * 32 + c31;
        bf16x8 v;
#pragma unroll
        for (int j = 0; j < 8; ++j) {
            int c2 = (t2 * 2 + (j >> 2)) * 8 + 4 * hf + (j & 3);
            v[j] = f2bf(tile[c2 * 264 + d] * en2s[c2]);
        }
        *(bf16x8*)&bg[ch * CHUNK_SH + (16 + g) * FRAG_SH + l * 8] = v;
    }
}

// ---------------- main fused kernel ----------------
__global__ __launch_bounds__(256, 2)
void svq_kernel(const float* __restrict__ z,
                const short* __restrict__ bg,
                float* __restrict__ out,
                float* __restrict__ loss) {
    __shared__ __align__(16) short lds_b[2 * CHUNK_SH];  // 2 x 32 KB double buffer

    const int tid = threadIdx.x;
    const int w = tid >> 6, l = tid & 63, hf = l >> 5, c31 = l & 31;
    const int rowbase = blockIdx.x * BLK_ROWS + w * 32;

    // z fragments: lane holds z[rowbase + c31][t*16 + hf*8 + j].
    // Same register layout serves as MFMA B-operand (B[k=d][n=row]) for GEMM1.
    bf16x8 za[16];
    float sz2 = 0.f;   // exact fp32 sum of z^2 over this lane's 128 elements
    {
        const float* zr = z + (size_t)(rowbase + c31) * DIM + hf * 8;
#pragma unroll
        for (int t = 0; t < 16; ++t) {
            float4 v0 = *(const float4*)(zr + t * 16);
            float4 v1 = *(const float4*)(zr + t * 16 + 4);
            sz2 += v0.x*v0.x + v0.y*v0.y + v0.z*v0.z + v0.w*v0.w
                 + v1.x*v1.x + v1.y*v1.y + v1.z*v1.z + v1.w*v1.w;
            bf16x8 a;
            a[0] = f2bf(v0.x); a[1] = f2bf(v0.y); a[2] = f2bf(v0.z); a[3] = f2bf(v0.w);
            a[4] = f2bf(v1.x); a[5] = f2bf(v1.y); a[6] = f2bf(v1.z); a[7] = f2bf(v1.w);
            za[t] = a;
        }
    }

    f32x16 o[8];
#pragma unroll
    for (int i = 0; i < 8; ++i)
        o[i] = (f32x16){0.f,0.f,0.f,0.f,0.f,0.f,0.f,0.f,0.f,0.f,0.f,0.f,0.f,0.f,0.f,0.f};
    float rs0 = 0.f, rs1 = 0.f;   // sum of p over this lane's codes (two partials)
    float q0 = 0.f,  q1 = 0.f;    // sum of p*s -> z_soft . z (two partials)

    // prologue: stage chunk 0 into buffer 0
    {
        const short* sg = bg + l * 8;
#pragma unroll
        for (int i = 0; i < 8; ++i) {
            int f = i * 4 + w;
            gload16(sg + f * FRAG_SH, &lds_b[f * FRAG_SH]);
        }
    }

    for (int ch = 0; ch < NCHUNK; ++ch) {
        // drains chunk-ch staging (which had all of compute(ch-1) to overlap)
        // and makes buffer (ch+1)&1 safe to overwrite
        __syncthreads();
        if (ch + 1 < NCHUNK) {
            const short* sg = bg + (ch + 1) * CHUNK_SH + l * 8;
            short* lbase = &lds_b[((ch + 1) & 1) * CHUNK_SH];
#pragma unroll
            for (int i = 0; i < 8; ++i) {
                int f = i * 4 + w;
                gload16(sg + f * FRAG_SH, lbase + f * FRAG_SH);
            }
        }

        const short* lb = &lds_b[(ch & 1) * CHUNK_SH + l * 8];

        // GEMM1 (transposed): S^T[32 codes x 32 rows] = E . Z^T
        f32x16 s = (f32x16){0.f,0.f,0.f,0.f,0.f,0.f,0.f,0.f,0.f,0.f,0.f,0.f,0.f,0.f,0.f,0.f};
#pragma unroll
        for (int t = 0; t < 16; ++t) {
            bf16x8 a = *(const bf16x8*)(lb + t * FRAG_SH);
            s = __builtin_amdgcn_mfma_f32_32x32x16_bf16(a, za[t], s, 0, 0, 0);
        }

        // softmax half 1 (regs 0..7 -> a20), then ISSUE its 8 GEMM2 MFMAs
        // immediately so they drain in the matrix pipe while the wave computes
        // half 2 on the VALU (MFMA issue is non-blocking for the wave).
        bf16x8 a20;
#pragma unroll
        for (int reg = 0; reg < 8; ++reg) {
            float sv = s[reg];
            float p = exp2f(sv * 2.8853900818f);   // exp(2 z.e)
            if (reg & 1) { rs1 += p; q1 += p * sv; }
            else         { rs0 += p; q0 += p * sv; }
            a20[reg] = f2bf(p);
        }
#pragma unroll
        for (int n2 = 0; n2 < 8; ++n2) {
            bf16x8 b0 = *(const bf16x8*)(lb + (16 + n2 * 2) * FRAG_SH);
            o[n2] = __builtin_amdgcn_mfma_f32_32x32x16_bf16(a20, b0, o[n2], 0, 0, 0);
        }

        // softmax half 2 (regs 8..15 -> a21), then its 8 GEMM2 MFMAs
        bf16x8 a21;
#pragma unroll
        for (int reg = 8; reg < 16; ++reg) {
            float sv = s[reg];
            float p = exp2f(sv * 2.8853900818f);
            if (reg & 1) { rs1 += p; q1 += p * sv; }
            else         { rs0 += p; q0 += p * sv; }
            a21[reg - 8] = f2bf(p);
        }
#pragma unroll
        for (int n2 = 0; n2 < 8; ++n2) {
            bf16x8 b1 = *(const bf16x8*)(lb + (16 + n2 * 2 + 1) * FRAG_SH);
            o[n2] = __builtin_amdgcn_mfma_f32_32x32x16_bf16(a21, b1, o[n2], 0, 0, 0);
        }
    }

    // combine the two half-dim/half-code lanes of each row
    float rs = rs0 + rs1, q = q0 + q1;
    float rs_t = rs + __shfl_xor(rs, 32, 64);
    float q_t  = q  + __shfl_xor(q, 32, 64);
    float inv  = 1.f / rs_t;

    // broadcast inv to the C-layout rows this lane will store
    float invr[16];
#pragma unroll
    for (int reg = 0; reg < 16; ++reg) {
        int r = (reg & 3) + 8 * (reg >> 2) + 4 * hf;
        invr[reg] = __shfl(inv, r, 64);
    }

    // epilogue: normalize, store, accumulate loss terms.
    // n2-outer order is measured-best for HBM write traffic (row-outer order
    // raised WRITE_SIZE 281->347 MB); do not "fix" this again.
    float zs2 = 0.f;
    const size_t ob = (size_t)rowbase * DIM;
#pragma unroll
    for (int n2 = 0; n2 < 8; ++n2) {
#pragma unroll
        for (int reg = 0; reg < 16; ++reg) {
            int r = (reg & 3) + 8 * (reg >> 2) + 4 * hf;
            float v = o[n2][reg] * invr[reg];
            out[ob + (size_t)r * DIM + n2 * 32 + c31] = v;
            zs2 += v * v;
        }
    }

    // loss = mean(z^2) - 2*mean(zs.z) + mean(zs^2); zs.z per row = q_t * inv
    float lacc = sz2 + zs2;
    if (hf == 0) lacc -= 2.f * q_t * inv;
#pragma unroll
    for (int off = 32; off > 0; off >>= 1) lacc += __shfl_xor(lacc, off, 64);
    if (l == 0) atomicAdd(loss, lacc * (1.f / ((float)N_ROWS * (float)DIM)));
}

extern "C" void kernel_launch(void* const* d_in, const int* in_sizes, int n_in,
                              void* d_out, int out_size, void* d_ws, size_t ws_size,
                              hipStream_t stream) {
    const float* z = (const float*)d_in[0];
    const float* cb = (const float*)d_in[1];
    float* out = (float*)d_out;

    short* bg = (short*)d_ws;    // 32 chunks * 16384 shorts = 1 MB

    float* loss = out + (size_t)N_ROWS * DIM;
    hipMemsetAsync((void*)loss, 0, sizeof(float), stream);

    prep_kernel<<<dim3(NCHUNK), dim3(256), 0, stream>>>(cb, bg);
    svq_kernel<<<dim3(N_ROWS / BLK_ROWS), dim3(256), 0, stream>>>(
        z, bg, out, loss);
}